// Round 1
// 1530.934 us; speedup vs baseline: 1.0279x; 1.0279x over previous
//
#include <hip/hip_runtime.h>
#include <hip/hip_bf16.h>

// ---------------- problem constants ----------------
#define L_    2048
#define DIM_  4096
#define H_    128
#define P_    64
#define G_    8
#define NST_  128      // state dim N
#define CS_   128      // chunk size
#define NC_   16       // L / CS
#define INTER_ 8192
#define CONVD_ 10240
#define NPROJ_ 18560   // INTER + CONVD + H

typedef unsigned short u16;
typedef __attribute__((ext_vector_type(8))) __bf16 bf16x8;
typedef __attribute__((ext_vector_type(4))) float f32x4;

// ---------------- helpers ----------------
__device__ __forceinline__ u16 f2bf(float f) {
  unsigned u = __float_as_uint(f);
  u += 0x7FFFu + ((u >> 16) & 1u);
  return (u16)(u >> 16);
}
__device__ __forceinline__ float bf2f(u16 v) {
  return __uint_as_float(((unsigned)v) << 16);
}
__device__ __forceinline__ float silu_f(float x) {
  return x / (1.f + expf(-x));
}

__device__ __forceinline__ f32x4 mfma_bf16(bf16x8 a, bf16x8 b, f32x4 c) {
  return __builtin_amdgcn_mfma_f32_16x16x32_bf16(a, b, c, 0, 0, 0);
}

// async global->LDS, 16B per lane. LDS dest must be linear (base + lane*16).
__device__ __forceinline__ void glds16(const u16* g, u16* l) {
  const auto* gp = (const __attribute__((address_space(1))) unsigned int*)(unsigned long long)(g);
  auto* lp = (__attribute__((address_space(3))) unsigned int*)(unsigned long long)(l);
  __builtin_amdgcn_global_load_lds(gp, lp, 16, 0, 0);
}

// ---------------- cast f32 -> bf16 ----------------
__global__ __launch_bounds__(256) void cast_k(const float* __restrict__ src,
                                              u16* __restrict__ dst, int n4) {
  int i = blockIdx.x * 256 + threadIdx.x;
  if (i >= n4) return;
  float4 v = ((const float4*)src)[i];
  ushort4 o = make_ushort4(f2bf(v.x), f2bf(v.y), f2bf(v.z), f2bf(v.w));
  ((ushort4*)dst)[i] = o;
}

// ---------------- GEMM: C[M][N] = A[M][K] * B[N][K]^T  (bf16 in, f32 out) ------
// m97 structure: BM=BN=128, BK=32, 256 threads (4 waves, each 64x64 out).
// Staging via global_load_lds width=16 into LINEAR LDS (no pad — required by
// the DMA's wave-uniform-base+lane*16 write pattern). 2 barriers per K-step.
// SWZ=1: bijective XCD-chunked blockIdx swizzle (requires nwg % 8 == 0).
template <int SWZ>
__global__ __launch_bounds__(256) void gemm_bt(const u16* __restrict__ A,
                                               const u16* __restrict__ B,
                                               float* __restrict__ C,
                                               int M, int N, int K) {
  __shared__ __align__(16) u16 sA[128 * 32];
  __shared__ __align__(16) u16 sB[128 * 32];
  const int nbm = M >> 7;
  int lin = blockIdx.x;
  if (SWZ) {
    const int ch = gridDim.x >> 3;          // nwg % 8 == 0 guaranteed by launcher
    lin = (lin & 7) * ch + (lin >> 3);
  }
  const int bm = (lin % nbm) << 7;
  const int bn = (lin / nbm) << 7;

  const int tid = threadIdx.x;
  const int lane = tid & 63, wv = tid >> 6;
  const int lr = lane & 15, kg = lane >> 4;
  const int wm = (wv >> 1) << 6, wn = (wv & 1) << 6;

  // staging: thread t covers row rs = t>>2 (and rs+64), 8-elem col group (t&3).
  // LDS offset = rs*32 + cs = tid*8 elements = tid*16 bytes -> wave-linear. OK.
  const int rs = tid >> 2, cs = (tid & 3) << 3;
  const u16* a0 = A + (size_t)(bm + rs) * K + cs;
  const u16* a1 = a0 + (size_t)64 * K;
  const u16* b0 = B + (size_t)(bn + rs) * K + cs;
  const u16* b1 = b0 + (size_t)64 * K;
  u16* sAp = &sA[tid * 8];
  u16* sBp = &sB[tid * 8];

  f32x4 acc[4][4] = {};
  for (int k0 = 0; k0 < K; k0 += 32) {
    __syncthreads();                 // prev compute done before overwrite
    glds16(a0, sAp);
    glds16(a1, sAp + 64 * 32);
    glds16(b0, sBp);
    glds16(b1, sBp + 64 * 32);
    a0 += 32; a1 += 32; b0 += 32; b1 += 32;
    __syncthreads();                 // compiler drains vmcnt(0) here (m97 structure)

    bf16x8 av[4], bv[4];
#pragma unroll
    for (int mi = 0; mi < 4; ++mi)
      av[mi] = *(const bf16x8*)&sA[(wm + mi * 16 + lr) * 32 + kg * 8];
#pragma unroll
    for (int ni = 0; ni < 4; ++ni)
      bv[ni] = *(const bf16x8*)&sB[(wn + ni * 16 + lr) * 32 + kg * 8];
#pragma unroll
    for (int mi = 0; mi < 4; ++mi)
#pragma unroll
      for (int ni = 0; ni < 4; ++ni)
        acc[mi][ni] = mfma_bf16(av[mi], bv[ni], acc[mi][ni]);
  }

#pragma unroll
  for (int mi = 0; mi < 4; ++mi)
#pragma unroll
    for (int ni = 0; ni < 4; ++ni) {
      f32x4 a4 = acc[mi][ni];
#pragma unroll
      for (int r = 0; r < 4; ++r) {
        int row = bm + wm + mi * 16 + kg * 4 + r;
        int col = bn + wn + ni * 16 + lr;
        C[(size_t)row * N + col] = a4[r];
      }
    }
}

// ---------------- depthwise causal conv (K=4) + bias + SiLU ----------------
__global__ __launch_bounds__(256) void conv_silu(const float* __restrict__ proj,
                                                 const float* __restrict__ cw,
                                                 const float* __restrict__ cb,
                                                 u16* __restrict__ xo,
                                                 u16* __restrict__ Bo,
                                                 u16* __restrict__ Co) {
  int ci = blockIdx.x * 256 + threadIdx.x;   // 0..CONVD-1
  int l = blockIdx.y;
  const float* w = cw + ci * 4;
  float a = cb[ci];
#pragma unroll
  for (int k = 0; k < 4; ++k) {
    int ls = l - 3 + k;
    if (ls >= 0) a += proj[(size_t)ls * NPROJ_ + INTER_ + ci] * w[k];
  }
  u16 bv = f2bf(silu_f(a));
  if (ci < INTER_)             xo[(size_t)l * INTER_ + ci] = bv;
  else if (ci < INTER_ + 1024) Bo[(size_t)l * 1024 + (ci - INTER_)] = bv;
  else                         Co[(size_t)l * 1024 + (ci - INTER_ - 1024)] = bv;
}

// ---------------- dt = softplus(raw + bias) ----------------
__global__ __launch_bounds__(256) void dt_k(const float* __restrict__ proj,
                                            const float* __restrict__ dt_bias,
                                            float* __restrict__ dtb) {
  int i = blockIdx.x * 256 + threadIdx.x;  // L*H
  int l = i >> 7, h = i & 127;
  float z = proj[(size_t)l * NPROJ_ + (INTER_ + CONVD_) + h] + dt_bias[h];
  dtb[i] = (z > 20.f) ? z : log1pf(expf(z));
}

// ---------------- SSM intra-chunk: Y_diag + D*x, chunk states, A_cumsum -------
// grid (NC, H), 256 threads. states layout: [c][h][p][n] (p-major).
__global__ __launch_bounds__(256) void ssm_intra(const u16* __restrict__ xb,
                                                 const u16* __restrict__ Bb,
                                                 const u16* __restrict__ Cb,
                                                 const float* __restrict__ dtb,
                                                 const float* __restrict__ A_log,
                                                 const float* __restrict__ Dp,
                                                 float* __restrict__ acum_g,
                                                 float* __restrict__ states,
                                                 float* __restrict__ Y) {
  __shared__ __align__(16) u16 bufM[128 * 136];  // M  [l][s]  -> later BdT [n][l]
  __shared__ __align__(16) u16 buf3[64 * 136];   // xdt^T [p][l]
  __shared__ float s_dt[128];
  __shared__ float s_ac[128];
  const int c = blockIdx.x, h = blockIdx.y, g = h >> 4;
  const int tid = threadIdx.x;
  const int lane = tid & 63, wv = tid >> 6;
  const int lr = lane & 15, kg = lane >> 4;

  // --- A*dt and inclusive cumsum over the chunk ---
  float Ah = -expf(A_log[h]);
  if (tid < 128) {
    float dv = dtb[(size_t)(c * 128 + tid) * 128 + h];
    s_dt[tid] = dv;
    s_ac[tid] = Ah * dv;
  }
  __syncthreads();
  for (int off = 1; off < 128; off <<= 1) {
    float v = 0.f;
    if (tid < 128 && tid >= off) v = s_ac[tid - off];
    __syncthreads();
    if (tid < 128) s_ac[tid] += v;
    __syncthreads();
  }
  if (tid < 128) acum_g[((size_t)c * 128 + h) * 128 + tid] = s_ac[tid];

  // --- build xdt^T [p][l] in buf3 (coalesced global read, transposed LDS write) ---
  for (int it = 0; it < 32; ++it) {
    int idx = tid + 256 * it;          // 8192 = 64p * 128l
    int p = idx & 63, srow = idx >> 6;
    float xv = bf2f(xb[(size_t)(c * 128 + srow) * INTER_ + h * 64 + p]);
    buf3[p * 136 + srow] = f2bf(xv * s_dt[srow]);
  }

  // --- phase 1: S[l][s] = sum_n C[l,n] B[s,n]  (fragments straight from global) ---
  const u16* Cbase = Cb + (size_t)c * 128 * 1024 + g * 128;
  const u16* Bbase = Bb + (size_t)c * 128 * 1024 + g * 128;
  const int wm = (wv >> 1) << 6, wn = (wv & 1) << 6;
  f32x4 S[4][4] = {};
  for (int ks = 0; ks < 128; ks += 32) {
    bf16x8 av[4], bv[4];
#pragma unroll
    for (int mi = 0; mi < 4; ++mi)
      av[mi] = *(const bf16x8*)(Cbase + (size_t)(wm + mi * 16 + lr) * 1024 + ks + kg * 8);
#pragma unroll
    for (int ni = 0; ni < 4; ++ni)
      bv[ni] = *(const bf16x8*)(Bbase + (size_t)(wn + ni * 16 + lr) * 1024 + ks + kg * 8);
#pragma unroll
    for (int mi = 0; mi < 4; ++mi)
#pragma unroll
      for (int ni = 0; ni < 4; ++ni)
        S[mi][ni] = mfma_bf16(av[mi], bv[ni], S[mi][ni]);
  }

  // --- phase 2: M = S * exp(ac[l]-ac[s]) masked l>=s -> bufM (bf16) ---
#pragma unroll
  for (int mi = 0; mi < 4; ++mi)
#pragma unroll
    for (int ni = 0; ni < 4; ++ni) {
      f32x4 sv = S[mi][ni];
#pragma unroll
      for (int r = 0; r < 4; ++r) {
        int l = wm + mi * 16 + kg * 4 + r;
        int s = wn + ni * 16 + lr;
        float mv = 0.f;
        if (l >= s) mv = sv[r] * expf(s_ac[l] - s_ac[s]);
        bufM[l * 136 + s] = f2bf(mv);
      }
    }
  __syncthreads();

  // --- phase 3: Y_diag[l][p] = sum_s M[l,s] * xdt[s,p]; add D*x; store Y ---
  f32x4 yacc[2][4] = {};
  for (int ks = 0; ks < 128; ks += 32) {
    bf16x8 am[2], bx[4];
#pragma unroll
    for (int mi = 0; mi < 2; ++mi)
      am[mi] = *(const bf16x8*)&bufM[(32 * wv + mi * 16 + lr) * 136 + ks + kg * 8];
#pragma unroll
    for (int ni = 0; ni < 4; ++ni)
      bx[ni] = *(const bf16x8*)&buf3[(ni * 16 + lr) * 136 + ks + kg * 8];
#pragma unroll
    for (int mi = 0; mi < 2; ++mi)
#pragma unroll
      for (int ni = 0; ni < 4; ++ni)
        yacc[mi][ni] = mfma_bf16(am[mi], bx[ni], yacc[mi][ni]);
  }
  float Dh = Dp[h];
#pragma unroll
  for (int mi = 0; mi < 2; ++mi)
#pragma unroll
    for (int ni = 0; ni < 4; ++ni) {
      f32x4 yv = yacc[mi][ni];
#pragma unroll
      for (int r = 0; r < 4; ++r) {
        int l = 32 * wv + mi * 16 + kg * 4 + r;
        int p = ni * 16 + lr;
        size_t o = (size_t)(c * 128 + l) * INTER_ + h * 64 + p;
        Y[o] = yv[r] + Dh * bf2f(xb[o]);
      }
    }

  // --- phase 4: chunk states[p][n] = sum_l xdt[l,p] * B[l,n]*exp(ac_last-ac[l]) ---
  float aclast = s_ac[127];
  __syncthreads();  // all waves done reading bufM
  for (int it = 0; it < 64; ++it) {
    int idx = tid + 256 * it;          // 16384 = 128n * 128l
    int n = idx & 127, lrow = idx >> 7;
    float bvv = bf2f(Bb[(size_t)(c * 128 + lrow) * 1024 + g * 128 + n]);
    bufM[n * 136 + lrow] = f2bf(bvv * expf(aclast - s_ac[lrow]));
  }
  __syncthreads();
  f32x4 st[8] = {};
  for (int ks = 0; ks < 128; ks += 32) {
    bf16x8 ax = *(const bf16x8*)&buf3[(16 * wv + lr) * 136 + ks + kg * 8];
#pragma unroll
    for (int ni = 0; ni < 8; ++ni) {
      bf16x8 bn = *(const bf16x8*)&bufM[(ni * 16 + lr) * 136 + ks + kg * 8];
      st[ni] = mfma_bf16(ax, bn, st[ni]);
    }
  }
#pragma unroll
  for (int ni = 0; ni < 8; ++ni) {
    f32x4 sv = st[ni];
#pragma unroll
    for (int r = 0; r < 4; ++r) {
      int p = 16 * wv + kg * 4 + r;
      int n = ni * 16 + lr;
      states[(((size_t)c * 128 + h) * 64 + p) * 128 + n] = sv[r];
    }
  }
}

// ---------------- inter-chunk recurrence (16 sequential steps) ----------------
__global__ __launch_bounds__(256) void scan_k(float* __restrict__ states,
                                              const float* __restrict__ acum_g) {
  int j = blockIdx.x * 256 + threadIdx.x;   // H*P*N = 1M
  int h = j >> 13;
  float run = 0.f;
  float* p = states + j;
  for (int c = 0; c < NC_; ++c) {
    float dk = expf(acum_g[((size_t)c * 128 + h) * 128 + 127]);
    float v = p[(size_t)c * 1048576];
    p[(size_t)c * 1048576] = run;          // prev-state entering chunk c
    run = run * dk + v;
  }
}

// ---------------- Y_off: C @ prev_states * exp(acum) added into Y ----------------
__global__ __launch_bounds__(256) void ssm_off(const u16* __restrict__ Cb,
                                               const float* __restrict__ states,
                                               const float* __restrict__ acum_g,
                                               float* __restrict__ Y) {
  const int c = blockIdx.x, h = blockIdx.y, g = h >> 4;
  const int tid = threadIdx.x, lane = tid & 63, wv = tid >> 6;
  const int lr = lane & 15, kg = lane >> 4;
  const u16* Cbase = Cb + (size_t)c * 128 * 1024 + g * 128;
  const float* sbase = states + ((size_t)c * 128 + h) * 64 * 128;
  f32x4 acc[2][4] = {};
  for (int ks = 0; ks < 128; ks += 32) {
    bf16x8 av[2], bv[4];
#pragma unroll
    for (int mi = 0; mi < 2; ++mi)
      av[mi] = *(const bf16x8*)(Cbase + (size_t)(32 * wv + mi * 16 + lr) * 1024 + ks + kg * 8);
#pragma unroll
    for (int ni = 0; ni < 4; ++ni) {
      const float* sp = sbase + (size_t)(ni * 16 + lr) * 128 + ks + kg * 8;
      float4 u0 = *(const float4*)sp;
      float4 u1 = *(const float4*)(sp + 4);
      union { bf16x8 v; u16 u[8]; } t;
      t.u[0] = f2bf(u0.x); t.u[1] = f2bf(u0.y); t.u[2] = f2bf(u0.z); t.u[3] = f2bf(u0.w);
      t.u[4] = f2bf(u1.x); t.u[5] = f2bf(u1.y); t.u[6] = f2bf(u1.z); t.u[7] = f2bf(u1.w);
      bv[ni] = t.v;
    }
#pragma unroll
    for (int mi = 0; mi < 2; ++mi)
#pragma unroll
      for (int ni = 0; ni < 4; ++ni)
        acc[mi][ni] = mfma_bf16(av[mi], bv[ni], acc[mi][ni]);
  }
  const float* ac = acum_g + ((size_t)c * 128 + h) * 128;
#pragma unroll
  for (int mi = 0; mi < 2; ++mi)
#pragma unroll
    for (int ni = 0; ni < 4; ++ni) {
      f32x4 a4 = acc[mi][ni];
#pragma unroll
      for (int r = 0; r < 4; ++r) {
        int l = 32 * wv + mi * 16 + kg * 4 + r;
        int p = ni * 16 + lr;
        size_t o = (size_t)(c * 128 + l) * INTER_ + h * 64 + p;
        Y[o] += expf(ac[l]) * a4[r];
      }
    }
}

// ---------------- RMSNorm * norm_w * silu(gate) -> bf16 ----------------
__global__ __launch_bounds__(256) void norm_gate(const float* __restrict__ Y,
                                                 const float* __restrict__ proj,
                                                 const float* __restrict__ norm_w,
                                                 u16* __restrict__ ybf) {
  const int l = blockIdx.x, tid = threadIdx.x;
  const float* yr = Y + (size_t)l * INTER_;
  float ss = 0.f;
  for (int i = tid; i < 2048; i += 256) {
    float4 v = ((const float4*)yr)[i];
    ss += v.x * v.x + v.y * v.y + v.z * v.z + v.w * v.w;
  }
  for (int off = 32; off > 0; off >>= 1) ss += __shfl_down(ss, off, 64);
  __shared__ float red[4];
  if ((tid & 63) == 0) red[tid >> 6] = ss;
  __syncthreads();
  float rs = rsqrtf((red[0] + red[1] + red[2] + red[3]) * (1.f / 8192.f) + 1e-5f);
  const float* gr = proj + (size_t)l * NPROJ_;
  for (int i = tid; i < 2048; i += 256) {
    float4 v = ((const float4*)yr)[i];
    float4 gv = ((const float4*)gr)[i];
    float4 nw = ((const float4*)norm_w)[i];
    ushort4 o = make_ushort4(f2bf(v.x * rs * nw.x * silu_f(gv.x)),
                             f2bf(v.y * rs * nw.y * silu_f(gv.y)),
                             f2bf(v.z * rs * nw.z * silu_f(gv.z)),
                             f2bf(v.w * rs * nw.w * silu_f(gv.w)));
    ((ushort4*)ybf)[(size_t)l * 2048 + i] = o;
  }
}

// ---------------- launcher ----------------
extern "C" void kernel_launch(void* const* d_in, const int* in_sizes, int n_in,
                              void* d_out, int out_size, void* d_ws, size_t ws_size,
                              hipStream_t stream) {
  const float* hs      = (const float*)d_in[0];
  const float* w_in    = (const float*)d_in[1];
  const float* conv_w  = (const float*)d_in[2];
  const float* conv_b  = (const float*)d_in[3];
  const float* dt_bias = (const float*)d_in[4];
  const float* A_log   = (const float*)d_in[5];
  const float* Dv      = (const float*)d_in[6];
  const float* norm_w  = (const float*)d_in[7];
  const float* w_out   = (const float*)d_in[8];
  float* out = (float*)d_out;

  char* ws = (char*)d_ws;
  // workspace layout (aliased where lifetimes allow; ~365 MB total)
  u16*   hs_bf   = (u16*)(ws + 0);                       // 16.8 MB
  u16*   win_bf  = (u16*)(ws + 16777216);                // 152 MB   [dead after GEMM1]
  float* states  = (float*)(ws + 16777216);              //   alias: 67 MB
  float* Yb      = (float*)(ws + 16777216 + 67108864);   //   alias: 67 MB
  float* proj    = (float*)(ws + 168820736);             // 152 MB   [gate needed until norm]
  u16*   wout_bf = (u16*)(ws + 168820736);               //   alias after norm: 67 MB
  u16*   xb      = (u16*)(ws + 320864256);               // 33.5 MB  [dead after ssm_intra]
  u16*   ybf     = (u16*)(ws + 320864256);               //   alias after norm write
  u16*   Bb      = (u16*)(ws + 354418688);               // 4.2 MB
  u16*   Cbuf    = (u16*)(ws + 358612992);               // 4.2 MB
  float* dtb     = (float*)(ws + 362807296);             // 1 MB
  float* acum    = (float*)(ws + 363855872);             // 1 MB

  // 1) casts to bf16
  cast_k<<<(L_ * DIM_ / 4 + 255) / 256, 256, 0, stream>>>(hs, hs_bf, L_ * DIM_ / 4);
  cast_k<<<(NPROJ_ * DIM_ / 4 + 255) / 256, 256, 0, stream>>>(w_in, win_bf, NPROJ_ * DIM_ / 4);
  // 2) in_proj GEMM: (2048 x 4096) @ (18560 x 4096)^T   [nwg = 16*145 = 2320, %8==0 -> SWZ]
  gemm_bt<1><<<dim3((L_ / 128) * (NPROJ_ / 128)), 256, 0, stream>>>(hs_bf, win_bf, proj, L_, NPROJ_, DIM_);
  // 3) depthwise conv + silu ; dt softplus
  conv_silu<<<dim3(CONVD_ / 256, L_), 256, 0, stream>>>(proj, conv_w, conv_b, xb, Bb, Cbuf);
  dt_k<<<(L_ * H_) / 256, 256, 0, stream>>>(proj, dt_bias, dtb);
  // 4) intra-chunk SSM
  ssm_intra<<<dim3(NC_, H_), 256, 0, stream>>>(xb, Bb, Cbuf, dtb, A_log, Dv, acum, states, Yb);
  // 5) inter-chunk recurrence
  scan_k<<<(H_ * P_ * NST_) / 256, 256, 0, stream>>>(states, acum);
  // 6) Y_off
  ssm_off<<<dim3(NC_, H_), 256, 0, stream>>>(Cbuf, states, acum, Yb);
  // 7) RMSNorm * silu(gate)
  norm_gate<<<L_, 256, 0, stream>>>(Yb, proj, norm_w, ybf);
  // 8) out_proj GEMM: (2048 x 8192) @ (4096 x 8192)^T   [footprint ~100MB L3-fit -> no SWZ]
  cast_k<<<(DIM_ * INTER_ / 4 + 255) / 256, 256, 0, stream>>>(w_out, wout_bf, DIM_ * INTER_ / 4);
  gemm_bt<0><<<dim3((L_ / 128) * (DIM_ / 128)), 256, 0, stream>>>(ybf, wout_bf, out, L_, DIM_, INTER_);
}

// Round 3
// 1390.176 us; speedup vs baseline: 1.1320x; 1.1013x over previous
//
#include <hip/hip_runtime.h>
#include <hip/hip_bf16.h>

// ---------------- problem constants ----------------
#define L_    2048
#define DIM_  4096
#define H_    128
#define P_    64
#define G_    8
#define NST_  128      // state dim N
#define CS_   128      // chunk size
#define NC_   16       // L / CS
#define INTER_ 8192
#define CONVD_ 10240
#define NPROJ_ 18560   // INTER + CONVD + H

typedef unsigned short u16;
typedef __attribute__((ext_vector_type(8))) __bf16 bf16x8;
typedef __attribute__((ext_vector_type(4))) float f32x4;

// ---------------- helpers ----------------
__device__ __forceinline__ u16 f2bf(float f) {
  unsigned u = __float_as_uint(f);
  u += 0x7FFFu + ((u >> 16) & 1u);
  return (u16)(u >> 16);
}
__device__ __forceinline__ float bf2f(u16 v) {
  return __uint_as_float(((unsigned)v) << 16);
}
__device__ __forceinline__ float silu_f(float x) {
  return x / (1.f + expf(-x));
}

__device__ __forceinline__ f32x4 mfma_bf16(bf16x8 a, bf16x8 b, f32x4 c) {
  return __builtin_amdgcn_mfma_f32_16x16x32_bf16(a, b, c, 0, 0, 0);
}

// async global->LDS, 16B per lane. LDS dest must be linear (base + lane*16).
__device__ __forceinline__ void glds16(const u16* g, u16* l) {
  const auto* gp = (const __attribute__((address_space(1))) unsigned int*)(unsigned long long)(g);
  auto* lp = (__attribute__((address_space(3))) unsigned int*)(unsigned long long)(l);
  __builtin_amdgcn_global_load_lds(gp, lp, 16, 0, 0);
}

#define S_BARRIER() asm volatile("s_barrier" ::: "memory")

// ---------------- cast f32 -> bf16 ----------------
__global__ __launch_bounds__(256) void cast_k(const float* __restrict__ src,
                                              u16* __restrict__ dst, int n4) {
  int i = blockIdx.x * 256 + threadIdx.x;
  if (i >= n4) return;
  float4 v = ((const float4*)src)[i];
  ushort4 o = make_ushort4(f2bf(v.x), f2bf(v.y), f2bf(v.z), f2bf(v.w));
  ((ushort4*)dst)[i] = o;
}

// ---------------- pipelined GEMM: C[M][N] = A[M][K] * B[N][K]^T ----------------
// 8-phase-style schedule (T2+T3+T4+T5): BN=256, BM=MI*32 (MI=8 -> 256, MI=4 -> 128),
// BK=32, 512 threads (8 waves as 2Mx4N, each wave 64-wide N, MI*16 rows M).
// 4-slot LDS ring: compute tile t from ring[t&3] while staging tile t+3 into
// ring[(t+3)&3] (slot freed at end of tile t-1 -> no read/write race).
// Counted vmcnt keeps 2 K-tiles of loads in flight; never drains to 0 mid-loop.
// LDS XOR-swizzle byte^=((byte>>3)&0x30) applied via pre-swizzled GLOBAL source
// (linear global_load_lds dest) + swizzled ds_read -> conflict-free b128 reads.
template <int MI, int SWZ>
__global__ __launch_bounds__(512) void gemm_p(const u16* __restrict__ A,
                                              const u16* __restrict__ B,
                                              float* __restrict__ C,
                                              int M, int N, int K, int nbm) {
  constexpr int BM = MI * 32;
  constexpr int ATILE2 = BM * 32;          // u16 per A K-tile
  constexpr int BTILE2 = 256 * 32;         // u16 per B K-tile
  constexpr int TILE2 = ATILE2 + BTILE2;   // u16 per ring slot
  constexpr int AJ = BM / 128;             // A glds16 per thread per tile (2 or 1)
  __shared__ __align__(16) u16 lds[4 * TILE2];   // 128 KiB (MI=8) / 96 KiB (MI=4)

  const int tid = threadIdx.x;
  const int lane = tid & 63, wv = tid >> 6;
  const int wvm = wv >> 2, wvn = wv & 3;
  const int lr = lane & 15, kg = lane >> 4;
  const int cofs = ((kg * 16) ^ ((lr << 3) & 0x30)) >> 1;  // swizzled col, u16 units

  int lin = blockIdx.x;
  if (SWZ) { const int ch = gridDim.x >> 3; lin = (lin & 7) * ch + (lin >> 3); }
  const int bm = (lin % nbm) * BM;
  const int bn = (lin / nbm) * 256;

  // staging precompute: LDS dest is thread-linear o = (j*512+tid)*16 bytes;
  // fetch global logical offset b = o ^ ((o>>3)&0x30) so swizzled data lands linear.
  const u16* gA[2];
  const u16* gB[2];
  int dA[2], dB[2];
#pragma unroll
  for (int j = 0; j < AJ; ++j) {
    int o = (j * 512 + tid) * 16;
    int b = o ^ ((o >> 3) & 0x30);
    gA[j] = A + (size_t)(bm + (b >> 6)) * K + ((b & 63) >> 1);
    dA[j] = o >> 1;
  }
#pragma unroll
  for (int j = 0; j < 2; ++j) {
    int o = (j * 512 + tid) * 16;
    int b = o ^ ((o >> 3) & 0x30);
    gB[j] = B + (size_t)(bn + (b >> 6)) * K + ((b & 63) >> 1);  // may over-read rows >= N (guarded at store)
    dB[j] = ATILE2 + (o >> 1);
  }

  const int NT = K >> 5;
  f32x4 acc[MI][4] = {};

  // ---- prologue: stage tiles 0,1,2; wait until tile 0 landed (keep 2 tiles in flight)
#pragma unroll
  for (int tt = 0; tt < 3; ++tt) {
#pragma unroll
    for (int j = 0; j < AJ; ++j) glds16(gA[j] + tt * 32, &lds[tt * TILE2 + dA[j]]);
#pragma unroll
    for (int j = 0; j < 2; ++j)  glds16(gB[j] + tt * 32, &lds[tt * TILE2 + dB[j]]);
  }
  if constexpr (AJ == 2) { asm volatile("s_waitcnt vmcnt(8)" ::: "memory"); }
  else                   { asm volatile("s_waitcnt vmcnt(6)" ::: "memory"); }
  S_BARRIER();

  for (int t = 0; t < NT; ++t) {
    const int rb = (t & 3) * TILE2;
    const int sb = ((t + 3) & 3) * TILE2;
    const bool st = (t + 3 < NT);
    const int abase = rb + (wvm * (MI * 16) + lr) * 32 + cofs;
    const int bbase = rb + ATILE2 + (wvn * 64 + lr) * 32 + cofs;

    bf16x8 av[4], bv[4];
#pragma unroll
    for (int mi = 0; mi < 4; ++mi) av[mi] = *(const bf16x8*)&lds[abase + mi * 512];
#pragma unroll
    for (int ni = 0; ni < 4; ++ni) bv[ni] = *(const bf16x8*)&lds[bbase + ni * 512];

    if constexpr (MI == 8) {
      // ---- phase 1: quadrant mi0-3, stage A of t+3 ----
      if (st) {
#pragma unroll
        for (int j = 0; j < 2; ++j) glds16(gA[j] + (t + 3) * 32, &lds[sb + dA[j]]);
      }
      S_BARRIER();
      __builtin_amdgcn_s_setprio(1);
#pragma unroll
      for (int mi = 0; mi < 4; ++mi)
#pragma unroll
        for (int ni = 0; ni < 4; ++ni)
          acc[mi][ni] = mfma_bf16(av[mi], bv[ni], acc[mi][ni]);
      __builtin_amdgcn_s_setprio(0);
      S_BARRIER();
      // ---- phase 2: quadrant mi4-7 (reuse bv), stage B of t+3 ----
      bf16x8 aw[4];
#pragma unroll
      for (int mi = 0; mi < 4; ++mi) aw[mi] = *(const bf16x8*)&lds[abase + (mi + 4) * 512];
      if (st) {
#pragma unroll
        for (int j = 0; j < 2; ++j) glds16(gB[j] + (t + 3) * 32, &lds[sb + dB[j]]);
      }
      S_BARRIER();
      __builtin_amdgcn_s_setprio(1);
#pragma unroll
      for (int mi = 0; mi < 4; ++mi)
#pragma unroll
        for (int ni = 0; ni < 4; ++ni)
          acc[mi + 4][ni] = mfma_bf16(aw[mi], bv[ni], acc[mi + 4][ni]);
      __builtin_amdgcn_s_setprio(0);
      if (st)              { asm volatile("s_waitcnt vmcnt(8)" ::: "memory"); }
      else if (t + 2 < NT) { asm volatile("s_waitcnt vmcnt(4)" ::: "memory"); }
      else if (t + 1 < NT) { asm volatile("s_waitcnt vmcnt(0)" ::: "memory"); }
      S_BARRIER();
    } else {
      // ---- single phase: 16 MFMA, stage A+B of t+3 ----
      if (st) {
        glds16(gA[0] + (t + 3) * 32, &lds[sb + dA[0]]);
#pragma unroll
        for (int j = 0; j < 2; ++j) glds16(gB[j] + (t + 3) * 32, &lds[sb + dB[j]]);
      }
      S_BARRIER();
      __builtin_amdgcn_s_setprio(1);
#pragma unroll
      for (int mi = 0; mi < 4; ++mi)
#pragma unroll
        for (int ni = 0; ni < 4; ++ni)
          acc[mi][ni] = mfma_bf16(av[mi], bv[ni], acc[mi][ni]);
      __builtin_amdgcn_s_setprio(0);
      if (st)              { asm volatile("s_waitcnt vmcnt(6)" ::: "memory"); }
      else if (t + 2 < NT) { asm volatile("s_waitcnt vmcnt(3)" ::: "memory"); }
      else if (t + 1 < NT) { asm volatile("s_waitcnt vmcnt(0)" ::: "memory"); }
      S_BARRIER();
    }
  }

  // ---- epilogue: C store (col-guarded for ragged N) ----
#pragma unroll
  for (int mi = 0; mi < MI; ++mi)
#pragma unroll
    for (int ni = 0; ni < 4; ++ni) {
      f32x4 a4 = acc[mi][ni];
#pragma unroll
      for (int r = 0; r < 4; ++r) {
        int row = bm + wvm * (MI * 16) + mi * 16 + kg * 4 + r;
        int col = bn + wvn * 64 + ni * 16 + lr;
        if (col < N) C[(size_t)row * N + col] = a4[r];
      }
    }
}

// ---------------- depthwise causal conv (K=4) + bias + SiLU ----------------
__global__ __launch_bounds__(256) void conv_silu(const float* __restrict__ proj,
                                                 const float* __restrict__ cw,
                                                 const float* __restrict__ cb,
                                                 u16* __restrict__ xo,
                                                 u16* __restrict__ Bo,
                                                 u16* __restrict__ Co) {
  int ci = blockIdx.x * 256 + threadIdx.x;   // 0..CONVD-1
  int l = blockIdx.y;
  const float* w = cw + ci * 4;
  float a = cb[ci];
#pragma unroll
  for (int k = 0; k < 4; ++k) {
    int ls = l - 3 + k;
    if (ls >= 0) a += proj[(size_t)ls * NPROJ_ + INTER_ + ci] * w[k];
  }
  u16 bv = f2bf(silu_f(a));
  if (ci < INTER_)             xo[(size_t)l * INTER_ + ci] = bv;
  else if (ci < INTER_ + 1024) Bo[(size_t)l * 1024 + (ci - INTER_)] = bv;
  else                         Co[(size_t)l * 1024 + (ci - INTER_ - 1024)] = bv;
}

// ---------------- dt = softplus(raw + bias) ----------------
__global__ __launch_bounds__(256) void dt_k(const float* __restrict__ proj,
                                            const float* __restrict__ dt_bias,
                                            float* __restrict__ dtb) {
  int i = blockIdx.x * 256 + threadIdx.x;  // L*H
  int l = i >> 7, h = i & 127;
  float z = proj[(size_t)l * NPROJ_ + (INTER_ + CONVD_) + h] + dt_bias[h];
  dtb[i] = (z > 20.f) ? z : log1pf(expf(z));
}

// ---------------- SSM intra-chunk: Y_diag + D*x, chunk states, A_cumsum -------
// grid (NC, H), 256 threads. states layout: [c][h][p][n] (p-major).
__global__ __launch_bounds__(256) void ssm_intra(const u16* __restrict__ xb,
                                                 const u16* __restrict__ Bb,
                                                 const u16* __restrict__ Cb,
                                                 const float* __restrict__ dtb,
                                                 const float* __restrict__ A_log,
                                                 const float* __restrict__ Dp,
                                                 float* __restrict__ acum_g,
                                                 float* __restrict__ states,
                                                 float* __restrict__ Y) {
  __shared__ __align__(16) u16 bufM[128 * 136];  // M  [l][s]  -> later BdT [n][l]
  __shared__ __align__(16) u16 buf3[64 * 136];   // xdt^T [p][l]
  __shared__ float s_dt[128];
  __shared__ float s_ac[128];
  const int c = blockIdx.x, h = blockIdx.y, g = h >> 4;
  const int tid = threadIdx.x;
  const int lane = tid & 63, wv = tid >> 6;
  const int lr = lane & 15, kg = lane >> 4;

  // --- A*dt and inclusive cumsum over the chunk ---
  float Ah = -expf(A_log[h]);
  if (tid < 128) {
    float dv = dtb[(size_t)(c * 128 + tid) * 128 + h];
    s_dt[tid] = dv;
    s_ac[tid] = Ah * dv;
  }
  __syncthreads();
  for (int off = 1; off < 128; off <<= 1) {
    float v = 0.f;
    if (tid < 128 && tid >= off) v = s_ac[tid - off];
    __syncthreads();
    if (tid < 128) s_ac[tid] += v;
    __syncthreads();
  }
  if (tid < 128) acum_g[((size_t)c * 128 + h) * 128 + tid] = s_ac[tid];

  // --- build xdt^T [p][l] in buf3 (coalesced global read, transposed LDS write) ---
  for (int it = 0; it < 32; ++it) {
    int idx = tid + 256 * it;          // 8192 = 64p * 128l
    int p = idx & 63, srow = idx >> 6;
    float xv = bf2f(xb[(size_t)(c * 128 + srow) * INTER_ + h * 64 + p]);
    buf3[p * 136 + srow] = f2bf(xv * s_dt[srow]);
  }

  // --- phase 1: S[l][s] = sum_n C[l,n] B[s,n]  (fragments straight from global) ---
  const u16* Cbase = Cb + (size_t)c * 128 * 1024 + g * 128;
  const u16* Bbase = Bb + (size_t)c * 128 * 1024 + g * 128;
  const int wm = (wv >> 1) << 6, wn = (wv & 1) << 6;
  f32x4 S[4][4] = {};
  for (int ks = 0; ks < 128; ks += 32) {
    bf16x8 av[4], bv[4];
#pragma unroll
    for (int mi = 0; mi < 4; ++mi)
      av[mi] = *(const bf16x8*)(Cbase + (size_t)(wm + mi * 16 + lr) * 1024 + ks + kg * 8);
#pragma unroll
    for (int ni = 0; ni < 4; ++ni)
      bv[ni] = *(const bf16x8*)(Bbase + (size_t)(wn + ni * 16 + lr) * 1024 + ks + kg * 8);
#pragma unroll
    for (int mi = 0; mi < 4; ++mi)
#pragma unroll
      for (int ni = 0; ni < 4; ++ni)
        S[mi][ni] = mfma_bf16(av[mi], bv[ni], S[mi][ni]);
  }

  // --- phase 2: M = S * exp(ac[l]-ac[s]) masked l>=s -> bufM (bf16) ---
#pragma unroll
  for (int mi = 0; mi < 4; ++mi)
#pragma unroll
    for (int ni = 0; ni < 4; ++ni) {
      f32x4 sv = S[mi][ni];
#pragma unroll
      for (int r = 0; r < 4; ++r) {
        int l = wm + mi * 16 + kg * 4 + r;
        int s = wn + ni * 16 + lr;
        float mv = 0.f;
        if (l >= s) mv = sv[r] * expf(s_ac[l] - s_ac[s]);
        bufM[l * 136 + s] = f2bf(mv);
      }
    }
  __syncthreads();

  // --- phase 3: Y_diag[l][p] = sum_s M[l,s] * xdt[s,p]; add D*x; store Y ---
  f32x4 yacc[2][4] = {};
  for (int ks = 0; ks < 128; ks += 32) {
    bf16x8 am[2], bx[4];
#pragma unroll
    for (int mi = 0; mi < 2; ++mi)
      am[mi] = *(const bf16x8*)&bufM[(32 * wv + mi * 16 + lr) * 136 + ks + kg * 8];
#pragma unroll
    for (int ni = 0; ni < 4; ++ni)
      bx[ni] = *(const bf16x8*)&buf3[(ni * 16 + lr) * 136 + ks + kg * 8];
#pragma unroll
    for (int mi = 0; mi < 2; ++mi)
#pragma unroll
      for (int ni = 0; ni < 4; ++ni)
        yacc[mi][ni] = mfma_bf16(am[mi], bx[ni], yacc[mi][ni]);
  }
  float Dh = Dp[h];
#pragma unroll
  for (int mi = 0; mi < 2; ++mi)
#pragma unroll
    for (int ni = 0; ni < 4; ++ni) {
      f32x4 yv = yacc[mi][ni];
#pragma unroll
      for (int r = 0; r < 4; ++r) {
        int l = 32 * wv + mi * 16 + kg * 4 + r;
        int p = ni * 16 + lr;
        size_t o = (size_t)(c * 128 + l) * INTER_ + h * 64 + p;
        Y[o] = yv[r] + Dh * bf2f(xb[o]);
      }
    }

  // --- phase 4: chunk states[p][n] = sum_l xdt[l,p] * B[l,n]*exp(ac_last-ac[l]) ---
  float aclast = s_ac[127];
  __syncthreads();  // all waves done reading bufM
  for (int it = 0; it < 64; ++it) {
    int idx = tid + 256 * it;          // 16384 = 128n * 128l
    int n = idx & 127, lrow = idx >> 7;
    float bvv = bf2f(Bb[(size_t)(c * 128 + lrow) * 1024 + g * 128 + n]);
    bufM[n * 136 + lrow] = f2bf(bvv * expf(aclast - s_ac[lrow]));
  }
  __syncthreads();
  f32x4 st[8] = {};
  for (int ks = 0; ks < 128; ks += 32) {
    bf16x8 ax = *(const bf16x8*)&buf3[(16 * wv + lr) * 136 + ks + kg * 8];
#pragma unroll
    for (int ni = 0; ni < 8; ++ni) {
      bf16x8 bn = *(const bf16x8*)&bufM[(ni * 16 + lr) * 136 + ks + kg * 8];
      st[ni] = mfma_bf16(ax, bn, st[ni]);
    }
  }
#pragma unroll
  for (int ni = 0; ni < 8; ++ni) {
    f32x4 sv = st[ni];
#pragma unroll
    for (int r = 0; r < 4; ++r) {
      int p = 16 * wv + kg * 4 + r;
      int n = ni * 16 + lr;
      states[(((size_t)c * 128 + h) * 64 + p) * 128 + n] = sv[r];
    }
  }
}

// ---------------- inter-chunk recurrence (16 sequential steps) ----------------
__global__ __launch_bounds__(256) void scan_k(float* __restrict__ states,
                                              const float* __restrict__ acum_g) {
  int j = blockIdx.x * 256 + threadIdx.x;   // H*P*N = 1M
  int h = j >> 13;
  float run = 0.f;
  float* p = states + j;
  for (int c = 0; c < NC_; ++c) {
    float dk = expf(acum_g[((size_t)c * 128 + h) * 128 + 127]);
    float v = p[(size_t)c * 1048576];
    p[(size_t)c * 1048576] = run;          // prev-state entering chunk c
    run = run * dk + v;
  }
}

// ---------------- Y_off: C @ prev_states * exp(acum) added into Y ----------------
__global__ __launch_bounds__(256) void ssm_off(const u16* __restrict__ Cb,
                                               const float* __restrict__ states,
                                               const float* __restrict__ acum_g,
                                               float* __restrict__ Y) {
  const int c = blockIdx.x, h = blockIdx.y, g = h >> 4;
  const int tid = threadIdx.x, lane = tid & 63, wv = tid >> 6;
  const int lr = lane & 15, kg = lane >> 4;
  const u16* Cbase = Cb + (size_t)c * 128 * 1024 + g * 128;
  const float* sbase = states + ((size_t)c * 128 + h) * 64 * 128;
  f32x4 acc[2][4] = {};
  for (int ks = 0; ks < 128; ks += 32) {
    bf16x8 av[2], bv[4];
#pragma unroll
    for (int mi = 0; mi < 2; ++mi)
      av[mi] = *(const bf16x8*)(Cbase + (size_t)(32 * wv + mi * 16 + lr) * 1024 + ks + kg * 8);
#pragma unroll
    for (int ni = 0; ni < 4; ++ni) {
      const float* sp = sbase + (size_t)(ni * 16 + lr) * 128 + ks + kg * 8;
      float4 u0 = *(const float4*)sp;
      float4 u1 = *(const float4*)(sp + 4);
      union { bf16x8 v; u16 u[8]; } t;
      t.u[0] = f2bf(u0.x); t.u[1] = f2bf(u0.y); t.u[2] = f2bf(u0.z); t.u[3] = f2bf(u0.w);
      t.u[4] = f2bf(u1.x); t.u[5] = f2bf(u1.y); t.u[6] = f2bf(u1.z); t.u[7] = f2bf(u1.w);
      bv[ni] = t.v;
    }
#pragma unroll
    for (int mi = 0; mi < 2; ++mi)
#pragma unroll
      for (int ni = 0; ni < 4; ++ni)
        acc[mi][ni] = mfma_bf16(av[mi], bv[ni], acc[mi][ni]);
  }
  const float* ac = acum_g + ((size_t)c * 128 + h) * 128;
#pragma unroll
  for (int mi = 0; mi < 2; ++mi)
#pragma unroll
    for (int ni = 0; ni < 4; ++ni) {
      f32x4 a4 = acc[mi][ni];
#pragma unroll
      for (int r = 0; r < 4; ++r) {
        int l = 32 * wv + mi * 16 + kg * 4 + r;
        int p = ni * 16 + lr;
        size_t o = (size_t)(c * 128 + l) * INTER_ + h * 64 + p;
        Y[o] += expf(ac[l]) * a4[r];
      }
    }
}

// ---------------- RMSNorm * norm_w * silu(gate) -> bf16 ----------------
__global__ __launch_bounds__(256) void norm_gate(const float* __restrict__ Y,
                                                 const float* __restrict__ proj,
                                                 const float* __restrict__ norm_w,
                                                 u16* __restrict__ ybf) {
  const int l = blockIdx.x, tid = threadIdx.x;
  const float* yr = Y + (size_t)l * INTER_;
  float ss = 0.f;
  for (int i = tid; i < 2048; i += 256) {
    float4 v = ((const float4*)yr)[i];
    ss += v.x * v.x + v.y * v.y + v.z * v.z + v.w * v.w;
  }
  for (int off = 32; off > 0; off >>= 1) ss += __shfl_down(ss, off, 64);
  __shared__ float red[4];
  if ((tid & 63) == 0) red[tid >> 6] = ss;
  __syncthreads();
  float rs = rsqrtf((red[0] + red[1] + red[2] + red[3]) * (1.f / 8192.f) + 1e-5f);
  const float* gr = proj + (size_t)l * NPROJ_;
  for (int i = tid; i < 2048; i += 256) {
    float4 v = ((const float4*)yr)[i];
    float4 gv = ((const float4*)gr)[i];
    float4 nw = ((const float4*)norm_w)[i];
    ushort4 o = make_ushort4(f2bf(v.x * rs * nw.x * silu_f(gv.x)),
                             f2bf(v.y * rs * nw.y * silu_f(gv.y)),
                             f2bf(v.z * rs * nw.z * silu_f(gv.z)),
                             f2bf(v.w * rs * nw.w * silu_f(gv.w)));
    ((ushort4*)ybf)[(size_t)l * 2048 + i] = o;
  }
}

// ---------------- launcher ----------------
extern "C" void kernel_launch(void* const* d_in, const int* in_sizes, int n_in,
                              void* d_out, int out_size, void* d_ws, size_t ws_size,
                              hipStream_t stream) {
  const float* hs      = (const float*)d_in[0];
  const float* w_in    = (const float*)d_in[1];
  const float* conv_w  = (const float*)d_in[2];
  const float* conv_b  = (const float*)d_in[3];
  const float* dt_bias = (const float*)d_in[4];
  const float* A_log   = (const float*)d_in[5];
  const float* Dv      = (const float*)d_in[6];
  const float* norm_w  = (const float*)d_in[7];
  const float* w_out   = (const float*)d_in[8];
  float* out = (float*)d_out;

  char* ws = (char*)d_ws;
  // workspace layout (aliased where lifetimes allow; ~365 MB total)
  u16*   hs_bf   = (u16*)(ws + 0);                       // 16.8 MB
  u16*   win_bf  = (u16*)(ws + 16777216);                // 152 MB   [dead after GEMM1]
  float* states  = (float*)(ws + 16777216);              //   alias: 67 MB
  float* Yb      = (float*)(ws + 16777216 + 67108864);   //   alias: 67 MB
  float* proj    = (float*)(ws + 168820736);             // 152 MB   [gate needed until norm]
  u16*   wout_bf = (u16*)(ws + 168820736);               //   alias after norm: 67 MB
  u16*   xb      = (u16*)(ws + 320864256);               // 33.5 MB  [dead after ssm_intra]
  u16*   ybf     = (u16*)(ws + 320864256);               //   alias after norm write
  u16*   Bb      = (u16*)(ws + 354418688);               // 4.2 MB
  u16*   Cbuf    = (u16*)(ws + 358612992);               // 4.2 MB
  float* dtb     = (float*)(ws + 362807296);             // 1 MB
  float* acum    = (float*)(ws + 363855872);             // 1 MB

  // 1) casts to bf16
  cast_k<<<(L_ * DIM_ / 4 + 255) / 256, 256, 0, stream>>>(hs, hs_bf, L_ * DIM_ / 4);
  cast_k<<<(NPROJ_ * DIM_ / 4 + 255) / 256, 256, 0, stream>>>(w_in, win_bf, NPROJ_ * DIM_ / 4);
  // 2) in_proj GEMM: (2048 x 4096) @ (18560 x 4096)^T
  //    256x256 tiles, grid 8*ceil(18560/256)=8*73=584 (%8==0 -> XCD swizzle);
  //    last N-tile ragged: B over-read lands in workspace (harmless), stores guarded.
  gemm_p<8, 1><<<dim3(8 * 73), 512, 0, stream>>>(hs_bf, win_bf, proj, L_, NPROJ_, DIM_, 8);
  // 3) depthwise conv + silu ; dt softplus
  conv_silu<<<dim3(CONVD_ / 256, L_), 256, 0, stream>>>(proj, conv_w, conv_b, xb, Bb, Cbuf);
  dt_k<<<(L_ * H_) / 256, 256, 0, stream>>>(proj, dt_bias, dtb);
  // 4) intra-chunk SSM
  ssm_intra<<<dim3(NC_, H_), 256, 0, stream>>>(xb, Bb, Cbuf, dtb, A_log, Dv, acum, states, Yb);
  // 5) inter-chunk recurrence
  scan_k<<<(H_ * P_ * NST_) / 256, 256, 0, stream>>>(states, acum);
  // 6) Y_off
  ssm_off<<<dim3(NC_, H_), 256, 0, stream>>>(Cbuf, states, acum, Yb);
  // 7) RMSNorm * silu(gate)
  norm_gate<<<L_, 256, 0, stream>>>(Yb, proj, norm_w, ybf);
  // 8) out_proj GEMM: (2048 x 8192) @ (4096 x 8192)^T
  //    128x256 tiles -> grid 16*16=256 blocks = exactly 1/CU (no tail quantization).
  cast_k<<<(DIM_ * INTER_ / 4 + 255) / 256, 256, 0, stream>>>(w_out, wout_bf, DIM_ * INTER_ / 4);
  gemm_p<4, 0><<<dim3(16 * 16), 512, 0, stream>>>(ybf, wout_bf, out, L_, DIM_, INTER_, 16);
}